// Round 1
// baseline (579.062 us; speedup 1.0000x reference)
//
#include <hip/hip_runtime.h>
#include <hip/hip_bf16.h>
#include <stdint.h>

// ---- problem constants ----
#define NB 50000   // batch of targets
#define NN 200000  // node table rows
#define KN 32      // neighbors per target
#define FD 256     // feature dim
#define F2 512     // concat dim
#define FO 256     // output dim

typedef __attribute__((ext_vector_type(8))) short short8v;   // 8 bf16 = 4 VGPRs (MFMA A/B frag)
typedef __attribute__((ext_vector_type(4))) short short4v;
typedef __attribute__((ext_vector_type(4))) float floatx4;   // MFMA C/D frag

__device__ inline short f2bf(float f) {
    __hip_bfloat16 h = __float2bfloat16(f);
    return *reinterpret_cast<short*>(&h);
}

// K0a: x_self (fp32 [NB][256]) -> H[:, 0:256] bf16, H is [NB][512]
__global__ void k_convert_xself(const float* __restrict__ x_self,
                                __hip_bfloat16* __restrict__ H) {
    int t = blockIdx.x * blockDim.x + threadIdx.x;   // 0 .. NB*FD/8-1
    if (t >= NB * FD / 8) return;
    int row = t >> 5;           // 32 threads per row
    int c8  = (t & 31) * 8;
    const float4* src = (const float4*)(x_self + (long)row * FD + c8);
    float4 a = src[0], b = src[1];
    short o[8] = { f2bf(a.x), f2bf(a.y), f2bf(a.z), f2bf(a.w),
                   f2bf(b.x), f2bf(b.y), f2bf(b.z), f2bf(b.w) };
    *(short8v*)((short*)H + (long)row * F2 + c8) = *(short8v*)o;
}

// K0b: W (fp32 [512][256] row-major, W[k][n]) -> bf16 pre-swizzled into MFMA
// B-fragment order: Wsw[((c*16 + t)*64 + l)*8 + j] = W[c*32 + (l>>4)*8 + j][t*16 + (l&15)]
// so the GEMM can stage each 32-k chunk with straight contiguous 16B copies.
__global__ void k_swizzle_W(const float* __restrict__ W,
                            __hip_bfloat16* __restrict__ Wsw) {
    int u = blockIdx.x * blockDim.x + threadIdx.x;   // 0..16383
    if (u >= 16 * 16 * 64) return;
    int c = u >> 10;          // k-chunk 0..15
    int t = (u >> 6) & 15;    // n-tile 0..15
    int l = u & 63;           // lane
    int kq = (l >> 4) * 8;
    int n  = t * 16 + (l & 15);
    short o[8];
#pragma unroll
    for (int j = 0; j < 8; ++j)
        o[j] = f2bf(W[(long)(c * 32 + kq + j) * FO + n]);
    *(short8v*)((short*)Wsw + (long)u * 8) = *(short8v*)o;
}

// K1: gather + mean -> H[:, 256:512] bf16. One wave per target row.
__global__ void k_gather_mean(const float* __restrict__ feats,
                              const int* __restrict__ idx,
                              __hip_bfloat16* __restrict__ H) {
    int wave = threadIdx.x >> 6;
    int lane = threadIdx.x & 63;
    int b = blockIdx.x * 4 + wave;
    if (b >= NB) return;
    const int* ib = idx + (long)b * KN;   // wave-uniform -> scalar loads
    int col = lane * 4;
    float ax = 0.f, ay = 0.f, az = 0.f, aw = 0.f;
#pragma unroll
    for (int k = 0; k < KN; ++k) {
        int id = ib[k];
        float4 v = *(const float4*)(feats + (long)id * FD + col);
        ax += v.x; ay += v.y; az += v.z; aw += v.w;
    }
    const float s = 1.0f / (float)KN;
    short o[4] = { f2bf(ax * s), f2bf(ay * s), f2bf(az * s), f2bf(aw * s) };
    *(short4v*)((short*)H + (long)b * F2 + FD + col) = *(short4v*)o;
}

// K2: out = H @ W + b via MFMA 16x16x32 bf16.
// Block = 128 threads (2 waves). Block tile: 64 rows x 256 cols, K=512.
// Each wave: 2 A-frags (32 rows), 16 N-tiles; B-frags from LDS reused across
// both A-frags (16 ds_read_b128 : 32 MFMA per k-chunk).
__global__ void __launch_bounds__(128)
k_gemm(const __hip_bfloat16* __restrict__ H,
       const __hip_bfloat16* __restrict__ Wsw,
       const float* __restrict__ bias,
       float* __restrict__ out) {
    __shared__ __hip_bfloat16 lW[16 * 64 * 8];   // 16 KB: one 32-k chunk, frag order

    int tid  = threadIdx.x;
    int wave = tid >> 6;
    int lane = tid & 63;
    int cl   = lane & 15;
    int quad = lane >> 4;
    int kq   = quad * 8;

    int mf0 = blockIdx.x * 64 + wave * 32;   // first 16-row frag
    int mf1 = mf0 + 16;                      // second 16-row frag
    bool v0 = mf0 < NB, v1 = mf1 < NB;
    long r0 = min(mf0 + cl, NB - 1);
    long r1 = min(mf1 + cl, NB - 1);

    floatx4 acc0[16], acc1[16];
#pragma unroll
    for (int t = 0; t < 16; ++t) { acc0[t] = (floatx4)(0.f); acc1[t] = (floatx4)(0.f); }

    for (int c = 0; c < 16; ++c) {
        // stage 16 KB W-chunk: wave w copies bytes [w*8192, w*8192+8192)
        const char* gsrc = (const char*)Wsw + (long)c * 16384;
#pragma unroll
        for (int i = 0; i < 8; ++i) {
            int off = wave * 8192 + i * 1024;   // wave-uniform LDS base per instr
            __builtin_amdgcn_global_load_lds(
                (__attribute__((address_space(1))) void*)(gsrc + off + lane * 16),
                (__attribute__((address_space(3))) void*)((char*)lW + off),
                16, 0, 0);
        }
        __syncthreads();

        short8v a0 = *(const short8v*)((const short*)H + r0 * F2 + c * 32 + kq);
        short8v a1 = *(const short8v*)((const short*)H + r1 * F2 + c * 32 + kq);
        const short8v* lw = (const short8v*)lW;
#pragma unroll
        for (int t = 0; t < 16; ++t) {
            short8v bf = lw[t * 64 + lane];
            acc0[t] = __builtin_amdgcn_mfma_f32_16x16x32_bf16(a0, bf, acc0[t], 0, 0, 0);
            acc1[t] = __builtin_amdgcn_mfma_f32_16x16x32_bf16(a1, bf, acc1[t], 0, 0, 0);
        }
        __syncthreads();
    }

    // epilogue: D row = quad*4 + reg, col = t*16 + cl
#pragma unroll
    for (int t = 0; t < 16; ++t) {
        float bv = bias[t * 16 + cl];
#pragma unroll
        for (int r = 0; r < 4; ++r) {
            if (v0) out[(long)(mf0 + quad * 4 + r) * FO + t * 16 + cl] = acc0[t][r] + bv;
            if (v1) out[(long)(mf1 + quad * 4 + r) * FO + t * 16 + cl] = acc1[t][r] + bv;
        }
    }
}

extern "C" void kernel_launch(void* const* d_in, const int* in_sizes, int n_in,
                              void* d_out, int out_size, void* d_ws, size_t ws_size,
                              hipStream_t stream) {
    const float* x_self = (const float*)d_in[0];
    const float* feats  = (const float*)d_in[1];
    const int*   idx    = (const int*)d_in[2];
    const float* W      = (const float*)d_in[3];
    const float* bias   = (const float*)d_in[4];
    float* out = (float*)d_out;

    // workspace layout
    __hip_bfloat16* H   = (__hip_bfloat16*)d_ws;                        // NB*512 bf16 = 51.2 MB
    __hip_bfloat16* Wsw = (__hip_bfloat16*)((char*)d_ws + (size_t)NB * F2 * 2);  // 256 KB

    k_convert_xself<<<NB * FD / 8 / 256, 256, 0, stream>>>(x_self, H);
    k_swizzle_W<<<64, 256, 0, stream>>>(W, Wsw);
    k_gather_mean<<<NB / 4, 256, 0, stream>>>(feats, idx, H);
    k_gemm<<<(NB + 63) / 64, 128, 0, stream>>>(H, Wsw, bias, out);
}

// Round 2
// 500.962 us; speedup vs baseline: 1.1559x; 1.1559x over previous
//
#include <hip/hip_runtime.h>
#include <hip/hip_bf16.h>
#include <stdint.h>

// ---- problem constants ----
#define NB 50000   // batch of targets
#define NN 200000  // node table rows
#define KN 32      // neighbors per target
#define FD 256     // feature dim
#define F2 512     // concat dim
#define FO 256     // output dim

typedef __attribute__((ext_vector_type(8))) short short8v;   // 8 bf16 (MFMA A/B frag)
typedef __attribute__((ext_vector_type(4))) short short4v;
typedef __attribute__((ext_vector_type(4))) float floatx4;   // MFMA C/D frag

__device__ inline short f2bf(float f) {
    __hip_bfloat16 h = __float2bfloat16(f);
    return *reinterpret_cast<short*>(&h);
}
__device__ inline float bf2f(short s) {
    unsigned u = ((unsigned)(unsigned short)s) << 16;
    return __builtin_bit_cast(float, u);
}

// K0: feats fp32 [NN*FD] -> bf16 Fb (halves the gather table: 205 -> 102 MB, fits L3)
__global__ void k_convert_feats(const float* __restrict__ feats,
                                __hip_bfloat16* __restrict__ Fb) {
    long t = (long)blockIdx.x * blockDim.x + threadIdx.x;  // one thread per 8 elems
    long base = t * 8;
    const float4* src = (const float4*)(feats + base);
    float4 a = src[0], b = src[1];
    short o[8] = { f2bf(a.x), f2bf(a.y), f2bf(a.z), f2bf(a.w),
                   f2bf(b.x), f2bf(b.y), f2bf(b.z), f2bf(b.w) };
    *(short8v*)((short*)Fb + base) = *(short8v*)o;
}

// K1: W fp32 [512][256] -> bf16, pre-swizzled into MFMA B-frag order, grouped by
// column-quarter so the GEMM stages one contiguous 64 KB block:
// Wsw[h*32768 + ((c*4 + tl)*64 + l)*8 + j] = W[c*32 + (l>>4)*8 + j][(h*4+tl)*16 + (l&15)]
__global__ void k_swizzle_W(const float* __restrict__ W,
                            __hip_bfloat16* __restrict__ Wsw) {
    int u = blockIdx.x * blockDim.x + threadIdx.x;   // 0..16383
    if (u >= 16384) return;
    int l  = u & 63;
    int tl = (u >> 6) & 3;
    int c  = (u >> 8) & 15;
    int h  = (u >> 12) & 3;
    int n  = (h * 4 + tl) * 16 + (l & 15);
    int kb = c * 32 + (l >> 4) * 8;
    short o[8];
#pragma unroll
    for (int j = 0; j < 8; ++j)
        o[j] = f2bf(W[(long)(kb + j) * FO + n]);
    *(short8v*)((short*)Wsw + (long)u * 8) = *(short8v*)o;
}

// K2: fused gather+mean (bf16 table) + x_self convert. One wave per target row.
// Writes H[b][0:256] = bf16(x_self[b]), H[b][256:512] = bf16(mean_k Fb[idx[b,k]]).
__global__ void k_gather_mean(const __hip_bfloat16* __restrict__ Fb,
                              const float* __restrict__ x_self,
                              const int* __restrict__ idx,
                              __hip_bfloat16* __restrict__ H) {
    int wave = threadIdx.x >> 6;
    int lane = threadIdx.x & 63;
    int b = blockIdx.x * 4 + wave;
    int c4 = lane * 4;

    // self half: fp32 -> bf16 passthrough
    float4 xs = *(const float4*)(x_self + (long)b * FD + c4);
    short so[4] = { f2bf(xs.x), f2bf(xs.y), f2bf(xs.z), f2bf(xs.w) };
    *(short4v*)((short*)H + (long)b * F2 + c4) = *(short4v*)so;

    // neighbor half: gather 32 bf16 rows, mean in fp32
    const int* ib = idx + (long)b * KN;   // wave-uniform
    float ax = 0.f, ay = 0.f, az = 0.f, aw = 0.f;
#pragma unroll
    for (int k = 0; k < KN; ++k) {
        int id = ib[k];
        short4v v = *(const short4v*)((const short*)Fb + (long)id * FD + c4);
        ax += bf2f(v.x); ay += bf2f(v.y); az += bf2f(v.z); aw += bf2f(v.w);
    }
    const float s = 1.0f / (float)KN;
    short o[4] = { f2bf(ax * s), f2bf(ay * s), f2bf(az * s), f2bf(aw * s) };
    *(short4v*)((short*)H + (long)b * F2 + FD + c4) = *(short4v*)o;
}

// K3: out = H @ W + b. Persistent-W GEMM: block = 256 thr (4 waves),
// tile = 256 rows x 64 cols, K=512. W column-quarter (64 KB) staged to LDS once,
// then a barrier-free K-loop: per chunk 4 B ds_read_b128 (reused over 4 A-frags),
// 4 A global 16B loads (H is L3-resident), 16 MFMAs.
__global__ void __launch_bounds__(256, 2)
k_gemm(const __hip_bfloat16* __restrict__ H,
       const __hip_bfloat16* __restrict__ Wsw,
       const float* __restrict__ bias,
       float* __restrict__ out) {
    __shared__ char lB[64 * 1024];   // 64 KB: one W column-quarter in frag order

    int tid  = threadIdx.x;
    int wave = tid >> 6;
    int lane = tid & 63;
    int cl   = lane & 15;
    int quad = lane >> 4;
    int kq   = quad * 8;

    int h  = blockIdx.x & 3;          // column-quarter (adjacent blocks share H rows)
    int rt = blockIdx.x >> 2;         // row tile

    // stage 64 KB W-quarter: 16 rounds x (256 threads x 16 B)
    const char* gsrc = (const char*)Wsw + (long)h * 65536;
#pragma unroll
    for (int i = 0; i < 16; ++i) {
        int off = i * 4096 + wave * 1024;   // wave-uniform LDS base, +lane*16 implicit
        __builtin_amdgcn_global_load_lds(
            (__attribute__((address_space(1))) void*)(gsrc + off + lane * 16),
            (__attribute__((address_space(3))) void*)(lB + off),
            16, 0, 0);
    }
    __syncthreads();

    int mf = rt * 256 + wave * 64;    // wave's first row; frags at mf, +16, +32, +48

    floatx4 acc[4][4];
#pragma unroll
    for (int f = 0; f < 4; ++f)
#pragma unroll
        for (int t = 0; t < 4; ++t) acc[f][t] = (floatx4)(0.f);

    const short8v* lb = (const short8v*)lB;
    for (int c = 0; c < 16; ++c) {
        short8v a[4];
#pragma unroll
        for (int f = 0; f < 4; ++f) {
            long r = min(mf + f * 16 + cl, NB - 1);
            a[f] = *(const short8v*)((const short*)H + r * F2 + c * 32 + kq);
        }
#pragma unroll
        for (int t = 0; t < 4; ++t) {
            short8v bf = lb[(c * 4 + t) * 64 + lane];
#pragma unroll
            for (int f = 0; f < 4; ++f)
                acc[f][t] = __builtin_amdgcn_mfma_f32_16x16x32_bf16(a[f], bf, acc[f][t], 0, 0, 0);
        }
    }

    // epilogue: D row = quad*4 + reg, col = cl (within 16-tile)
#pragma unroll
    for (int t = 0; t < 4; ++t) {
        int n = h * 64 + t * 16 + cl;
        float bv = bias[n];
#pragma unroll
        for (int f = 0; f < 4; ++f) {
            int row = mf + f * 16 + quad * 4;
#pragma unroll
            for (int r = 0; r < 4; ++r) {
                if (row + r < NB)
                    out[(long)(row + r) * FO + n] = acc[f][t][r] + bv;
            }
        }
    }
}

extern "C" void kernel_launch(void* const* d_in, const int* in_sizes, int n_in,
                              void* d_out, int out_size, void* d_ws, size_t ws_size,
                              hipStream_t stream) {
    const float* x_self = (const float*)d_in[0];
    const float* feats  = (const float*)d_in[1];
    const int*   idx    = (const int*)d_in[2];
    const float* W      = (const float*)d_in[3];
    const float* bias   = (const float*)d_in[4];
    float* out = (float*)d_out;

    // workspace layout
    __hip_bfloat16* Fb  = (__hip_bfloat16*)d_ws;                                   // 102.4 MB
    __hip_bfloat16* H   = (__hip_bfloat16*)((char*)d_ws + (size_t)NN * FD * 2);    // 51.2 MB
    __hip_bfloat16* Wsw = (__hip_bfloat16*)((char*)d_ws + (size_t)NN * FD * 2
                                                        + (size_t)NB * F2 * 2);    // 256 KB

    k_convert_feats<<<NN * FD / 8 / 256, 256, 0, stream>>>(feats, Fb);
    k_swizzle_W<<<64, 256, 0, stream>>>(W, Wsw);
    k_gather_mean<<<NB / 4, 256, 0, stream>>>(Fb, x_self, idx, H);
    k_gemm<<<4 * ((NB + 255) / 256), 256, 0, stream>>>(H, Wsw, bias, out);
}

// Round 3
// 440.262 us; speedup vs baseline: 1.3153x; 1.1379x over previous
//
#include <hip/hip_runtime.h>
#include <hip/hip_bf16.h>
#include <stdint.h>

// ---- problem constants ----
#define NB 50000   // batch of targets
#define NN 200000  // node table rows
#define KN 32      // neighbors per target
#define FD 256     // feature dim
#define F2 512     // concat dim
#define FO 256     // output dim

typedef __attribute__((ext_vector_type(8))) short short8v;   // 8 bf16 (MFMA A/B frag)
typedef __attribute__((ext_vector_type(4))) short short4v;
typedef __attribute__((ext_vector_type(4))) float floatx4;   // MFMA C/D frag
typedef __attribute__((ext_vector_type(2))) float float2v;

__device__ inline short f2bf(float f) {
    __hip_bfloat16 h = __float2bfloat16(f);
    return *reinterpret_cast<short*>(&h);
}

// K0: feats fp32 [NN*FD] -> fp8 e4m3 Q (205 -> 51.2 MB table; random-gather
// working set now small enough for strong L2/L3 residency).
__global__ void k_quant_feats(const float* __restrict__ feats,
                              unsigned char* __restrict__ Q) {
    long t = (long)blockIdx.x * blockDim.x + threadIdx.x;  // one thread per 8 elems
    long base = t * 8;
    const float4* src = (const float4*)(feats + base);
    float4 a = src[0], b = src[1];
    int lo = 0, hi = 0;
    lo = __builtin_amdgcn_cvt_pk_fp8_f32(a.x, a.y, lo, false);  // bytes 0,1
    lo = __builtin_amdgcn_cvt_pk_fp8_f32(a.z, a.w, lo, true);   // bytes 2,3
    hi = __builtin_amdgcn_cvt_pk_fp8_f32(b.x, b.y, hi, false);
    hi = __builtin_amdgcn_cvt_pk_fp8_f32(b.z, b.w, hi, true);
    int2 o = { lo, hi };
    *(int2*)(Q + base) = o;
}

// K1: W fp32 [512][256] -> bf16, pre-swizzled into MFMA B-frag order, grouped by
// column-quarter so the GEMM stages one contiguous 64 KB block:
// Wsw[h*32768 + ((c*4 + tl)*64 + l)*8 + j] = W[c*32 + (l>>4)*8 + j][(h*4+tl)*16 + (l&15)]
__global__ void k_swizzle_W(const float* __restrict__ W,
                            __hip_bfloat16* __restrict__ Wsw) {
    int u = blockIdx.x * blockDim.x + threadIdx.x;   // 0..16383
    if (u >= 16384) return;
    int l  = u & 63;
    int tl = (u >> 6) & 3;
    int c  = (u >> 8) & 15;
    int h  = (u >> 12) & 3;
    int n  = (h * 4 + tl) * 16 + (l & 15);
    int kb = c * 32 + (l >> 4) * 8;
    short o[8];
#pragma unroll
    for (int j = 0; j < 8; ++j)
        o[j] = f2bf(W[(long)(kb + j) * FO + n]);
    *(short8v*)((short*)Wsw + (long)u * 8) = *(short8v*)o;
}

// K2: fused gather+mean (fp8 table) + x_self convert. One wave per target row.
// H[b][0:256] = bf16(x_self[b]); H[b][256:512] = bf16(mean_k fp8(Q[idx[b,k]])).
__global__ void k_gather_mean(const unsigned char* __restrict__ Q,
                              const float* __restrict__ x_self,
                              const int* __restrict__ idx,
                              __hip_bfloat16* __restrict__ H) {
    int wave = threadIdx.x >> 6;
    int lane = threadIdx.x & 63;
    int b = blockIdx.x * 4 + wave;
    int c4 = lane * 4;

    // self half: fp32 -> bf16 passthrough
    float4 xs = *(const float4*)(x_self + (long)b * FD + c4);
    short so[4] = { f2bf(xs.x), f2bf(xs.y), f2bf(xs.z), f2bf(xs.w) };
    *(short4v*)((short*)H + (long)b * F2 + c4) = *(short4v*)so;

    // neighbor half: gather 32 fp8 rows (4 B/lane, 256 B/row coalesced), mean in fp32
    const int* ib = idx + (long)b * KN;   // wave-uniform
    float ax = 0.f, ay = 0.f, az = 0.f, aw = 0.f;
#pragma unroll
    for (int k = 0; k < KN; ++k) {
        int id = ib[k];
        int v = *(const int*)(Q + (long)id * FD + c4);
        float2v lo = __builtin_amdgcn_cvt_pk_f32_fp8(v, false);  // bytes 0,1
        float2v hi = __builtin_amdgcn_cvt_pk_f32_fp8(v, true);   // bytes 2,3
        ax += lo.x; ay += lo.y; az += hi.x; aw += hi.y;
    }
    const float s = 1.0f / (float)KN;
    short o[4] = { f2bf(ax * s), f2bf(ay * s), f2bf(az * s), f2bf(aw * s) };
    *(short4v*)((short*)H + (long)b * F2 + FD + c4) = *(short4v*)o;
}

// K3: out = H @ W + b. Persistent-W GEMM: block = 256 thr (4 waves),
// tile = 256 rows x 64 cols, K=512. W column-quarter (64 KB) staged to LDS once,
// then a barrier-free K-loop: per chunk 4 B ds_read_b128 (reused over 4 A-frags),
// 4 A global 16B loads (H is L2/L3-resident), 16 MFMAs.
__global__ void __launch_bounds__(256, 2)
k_gemm(const __hip_bfloat16* __restrict__ H,
       const __hip_bfloat16* __restrict__ Wsw,
       const float* __restrict__ bias,
       float* __restrict__ out) {
    __shared__ char lB[64 * 1024];   // 64 KB: one W column-quarter in frag order

    int tid  = threadIdx.x;
    int wave = tid >> 6;
    int lane = tid & 63;
    int cl   = lane & 15;
    int quad = lane >> 4;
    int kq   = quad * 8;

    int h  = blockIdx.x & 3;          // column-quarter (adjacent blocks share H rows)
    int rt = blockIdx.x >> 2;         // row tile

    // stage 64 KB W-quarter: 16 rounds x (256 threads x 16 B)
    const char* gsrc = (const char*)Wsw + (long)h * 65536;
#pragma unroll
    for (int i = 0; i < 16; ++i) {
        int off = i * 4096 + wave * 1024;   // wave-uniform LDS base, +lane*16 implicit
        __builtin_amdgcn_global_load_lds(
            (__attribute__((address_space(1))) void*)(gsrc + off + lane * 16),
            (__attribute__((address_space(3))) void*)(lB + off),
            16, 0, 0);
    }
    __syncthreads();

    int mf = rt * 256 + wave * 64;    // wave's first row; frags at mf, +16, +32, +48

    floatx4 acc[4][4];
#pragma unroll
    for (int f = 0; f < 4; ++f)
#pragma unroll
        for (int t = 0; t < 4; ++t) acc[f][t] = (floatx4)(0.f);

    const short8v* lb = (const short8v*)lB;
    for (int c = 0; c < 16; ++c) {
        short8v a[4];
#pragma unroll
        for (int f = 0; f < 4; ++f) {
            long r = min(mf + f * 16 + cl, NB - 1);
            a[f] = *(const short8v*)((const short*)H + r * F2 + c * 32 + kq);
        }
#pragma unroll
        for (int t = 0; t < 4; ++t) {
            short8v bf = lb[(c * 4 + t) * 64 + lane];
#pragma unroll
            for (int f = 0; f < 4; ++f)
                acc[f][t] = __builtin_amdgcn_mfma_f32_16x16x32_bf16(a[f], bf, acc[f][t], 0, 0, 0);
        }
    }

    // epilogue: D row = quad*4 + reg, col = cl (within 16-tile)
#pragma unroll
    for (int t = 0; t < 4; ++t) {
        int n = h * 64 + t * 16 + cl;
        float bv = bias[n];
#pragma unroll
        for (int f = 0; f < 4; ++f) {
            int row = mf + f * 16 + quad * 4;
#pragma unroll
            for (int r = 0; r < 4; ++r) {
                if (row + r < NB)
                    out[(long)(row + r) * FO + n] = acc[f][t][r] + bv;
            }
        }
    }
}

extern "C" void kernel_launch(void* const* d_in, const int* in_sizes, int n_in,
                              void* d_out, int out_size, void* d_ws, size_t ws_size,
                              hipStream_t stream) {
    const float* x_self = (const float*)d_in[0];
    const float* feats  = (const float*)d_in[1];
    const int*   idx    = (const int*)d_in[2];
    const float* W      = (const float*)d_in[3];
    const float* bias   = (const float*)d_in[4];
    float* out = (float*)d_out;

    // workspace layout
    unsigned char*  Q   = (unsigned char*)d_ws;                                    // 51.2 MB fp8
    __hip_bfloat16* H   = (__hip_bfloat16*)((char*)d_ws + (size_t)NN * FD);        // 51.2 MB bf16
    __hip_bfloat16* Wsw = (__hip_bfloat16*)((char*)d_ws + (size_t)NN * FD
                                                        + (size_t)NB * F2 * 2);    // 256 KB

    k_quant_feats<<<NN * FD / 8 / 256, 256, 0, stream>>>(feats, Q);
    k_swizzle_W<<<64, 256, 0, stream>>>(W, Wsw);
    k_gather_mean<<<NB / 4, 256, 0, stream>>>(Q, x_self, idx, H);
    k_gemm<<<4 * ((NB + 255) / 256), 256, 0, stream>>>(H, Wsw, bias, out);
}

// Round 4
// 429.109 us; speedup vs baseline: 1.3495x; 1.0260x over previous
//
#include <hip/hip_runtime.h>
#include <hip/hip_bf16.h>
#include <stdint.h>

// ---- problem constants ----
#define NB 50000   // batch of targets
#define NN 200000  // node table rows
#define KN 32      // neighbors per target
#define FD 256     // feature dim
#define F2 512     // concat dim
#define FO 256     // output dim

typedef __attribute__((ext_vector_type(8))) short short8v;   // 8 bf16 (MFMA A/B frag)
typedef __attribute__((ext_vector_type(4))) short short4v;
typedef __attribute__((ext_vector_type(4))) float floatx4;   // MFMA C/D frag
typedef __attribute__((ext_vector_type(2))) float float2v;

__device__ inline short f2bf(float f) {
    __hip_bfloat16 h = __float2bfloat16(f);
    return *reinterpret_cast<short*>(&h);
}

// K0: feats fp32 [NN*FD] -> fp8 e4m3 Q (205 -> 51.2 MB table). At the HBM floor
// (256 MB traffic ~= 42 us).
__global__ void k_quant_feats(const float* __restrict__ feats,
                              unsigned char* __restrict__ Q) {
    long t = (long)blockIdx.x * blockDim.x + threadIdx.x;  // one thread per 8 elems
    long base = t * 8;
    const float4* src = (const float4*)(feats + base);
    float4 a = src[0], b = src[1];
    int lo = 0, hi = 0;
    lo = __builtin_amdgcn_cvt_pk_fp8_f32(a.x, a.y, lo, false);
    lo = __builtin_amdgcn_cvt_pk_fp8_f32(a.z, a.w, lo, true);
    hi = __builtin_amdgcn_cvt_pk_fp8_f32(b.x, b.y, hi, false);
    hi = __builtin_amdgcn_cvt_pk_fp8_f32(b.z, b.w, hi, true);
    int2 o = { lo, hi };
    *(int2*)(Q + base) = o;
}

// K1: W fp32 [512][256] -> bf16 in linear MFMA B-frag order:
// Wsw[((c*16 + t)*64 + l)*8 + j] = W[c*32 + (l>>4)*8 + j][t*16 + (l&15)]
// 256 KB total -> L2-resident; GEMM reads B-frags straight from global.
__global__ void k_swizzle_W(const float* __restrict__ W,
                            __hip_bfloat16* __restrict__ Wsw) {
    int u = blockIdx.x * blockDim.x + threadIdx.x;   // 0..16383
    if (u >= 16384) return;
    int c = u >> 10;          // k-chunk 0..15
    int t = (u >> 6) & 15;    // n-tile 0..15
    int l = u & 63;           // lane
    int kq = (l >> 4) * 8;
    int n  = t * 16 + (l & 15);
    short o[8];
#pragma unroll
    for (int j = 0; j < 8; ++j)
        o[j] = f2bf(W[(long)(c * 32 + kq + j) * FO + n]);
    *(short8v*)((short*)Wsw + (long)u * 8) = *(short8v*)o;
}

// K2: gather + mean from fp8 table -> Hn bf16 [NB][256]. One wave per target.
// 16 B/lane => 4 neighbor rows per load instr (1 KB/instr); quad q covers
// neighbors 4k+q; cols cl*16..cl*16+15 per lane; fp32 packed accumulate;
// butterfly reduce across quads at the end.
__global__ void k_gather_mean(const unsigned char* __restrict__ Q,
                              const int* __restrict__ idx,
                              __hip_bfloat16* __restrict__ Hn) {
    int wave = threadIdx.x >> 6;
    int lane = threadIdx.x & 63;
    int b = blockIdx.x * 4 + wave;
    int cl   = lane & 15;
    int quad = lane >> 4;

    const int* ib = idx + (long)b * KN;
    float2v acc2[8];
#pragma unroll
    for (int j = 0; j < 8; ++j) acc2[j] = (float2v)(0.f);

#pragma unroll
    for (int k = 0; k < 8; ++k) {
        int nid = ib[4 * k + quad];
        int4 v = *(const int4*)(Q + (long)nid * FD + cl * 16);
        acc2[0] += __builtin_amdgcn_cvt_pk_f32_fp8(v.x, false);
        acc2[1] += __builtin_amdgcn_cvt_pk_f32_fp8(v.x, true);
        acc2[2] += __builtin_amdgcn_cvt_pk_f32_fp8(v.y, false);
        acc2[3] += __builtin_amdgcn_cvt_pk_f32_fp8(v.y, true);
        acc2[4] += __builtin_amdgcn_cvt_pk_f32_fp8(v.z, false);
        acc2[5] += __builtin_amdgcn_cvt_pk_f32_fp8(v.z, true);
        acc2[6] += __builtin_amdgcn_cvt_pk_f32_fp8(v.w, false);
        acc2[7] += __builtin_amdgcn_cvt_pk_f32_fp8(v.w, true);
    }

    // reduce the 4 quad-partials (each holds 8 of the 32 neighbors)
#pragma unroll
    for (int j = 0; j < 8; ++j) {
        acc2[j].x += __shfl_xor(acc2[j].x, 16);
        acc2[j].y += __shfl_xor(acc2[j].y, 16);
        acc2[j].x += __shfl_xor(acc2[j].x, 32);
        acc2[j].y += __shfl_xor(acc2[j].y, 32);
    }

    // lane writes cols cl*16 + quad*4 .. +3  (select acc2[2*quad], acc2[2*quad+1])
    float2v p0 = (quad & 1) ? acc2[2] : acc2[0];
    float2v p1 = (quad & 1) ? acc2[3] : acc2[1];
    float2v q0 = (quad & 1) ? acc2[6] : acc2[4];
    float2v q1 = (quad & 1) ? acc2[7] : acc2[5];
    float2v s0 = (quad & 2) ? q0 : p0;
    float2v s1 = (quad & 2) ? q1 : p1;
    const float s = 1.0f / (float)KN;
    short o[4] = { f2bf(s0.x * s), f2bf(s0.y * s), f2bf(s1.x * s), f2bf(s1.y * s) };
    *(short4v*)((short*)Hn + (long)b * FD + cl * 16 + quad * 4) = *(short4v*)o;
}

// K3: out = [x_self | Hn] @ W + b. Barrier-free, LDS-free MFMA GEMM.
// Block = 128 thr (2 waves); wave = 32 rows x 256 cols (2 A-frags x 16 N-tiles).
// A chunks 0-7 from x_self fp32 (convert in-register), chunks 8-15 from Hn bf16.
// B-frags straight from global Wsw (256 KB, L2-resident). H read ONCE.
__global__ void __launch_bounds__(128, 2)
k_gemm(const float* __restrict__ x_self,
       const __hip_bfloat16* __restrict__ Hn,
       const __hip_bfloat16* __restrict__ Wsw,
       const float* __restrict__ bias,
       float* __restrict__ out) {
    int wave = threadIdx.x >> 6;
    int lane = threadIdx.x & 63;
    int cl   = lane & 15;
    int quad = lane >> 4;
    int kq   = quad * 8;

    int mf = blockIdx.x * 64 + wave * 32;
    long r0 = min(mf + cl, NB - 1);
    long r1 = min(mf + 16 + cl, NB - 1);

    floatx4 acc[2][16];
#pragma unroll
    for (int f = 0; f < 2; ++f)
#pragma unroll
        for (int t = 0; t < 16; ++t) acc[f][t] = (floatx4)(0.f);

    const short8v* wp = (const short8v*)Wsw;

    // chunks 0..7: self half (x_self fp32 -> bf16 in-register)
#pragma unroll
    for (int c = 0; c < 8; ++c) {
        float4 p0 = *(const float4*)(x_self + r0 * FD + c * 32 + kq);
        float4 p1 = *(const float4*)(x_self + r0 * FD + c * 32 + kq + 4);
        float4 p2 = *(const float4*)(x_self + r1 * FD + c * 32 + kq);
        float4 p3 = *(const float4*)(x_self + r1 * FD + c * 32 + kq + 4);
        short a0s[8] = { f2bf(p0.x), f2bf(p0.y), f2bf(p0.z), f2bf(p0.w),
                         f2bf(p1.x), f2bf(p1.y), f2bf(p1.z), f2bf(p1.w) };
        short a1s[8] = { f2bf(p2.x), f2bf(p2.y), f2bf(p2.z), f2bf(p2.w),
                         f2bf(p3.x), f2bf(p3.y), f2bf(p3.z), f2bf(p3.w) };
        short8v a0 = *(short8v*)a0s;
        short8v a1 = *(short8v*)a1s;
#pragma unroll
        for (int t = 0; t < 16; ++t) {
            short8v bf = wp[(c * 16 + t) * 64 + lane];
            acc[0][t] = __builtin_amdgcn_mfma_f32_16x16x32_bf16(a0, bf, acc[0][t], 0, 0, 0);
            acc[1][t] = __builtin_amdgcn_mfma_f32_16x16x32_bf16(a1, bf, acc[1][t], 0, 0, 0);
        }
    }

    // chunks 8..15: neighbor half (Hn bf16)
#pragma unroll
    for (int c = 0; c < 8; ++c) {
        short8v a0 = *(const short8v*)((const short*)Hn + r0 * FD + c * 32 + kq);
        short8v a1 = *(const short8v*)((const short*)Hn + r1 * FD + c * 32 + kq);
#pragma unroll
        for (int t = 0; t < 16; ++t) {
            short8v bf = wp[((c + 8) * 16 + t) * 64 + lane];
            acc[0][t] = __builtin_amdgcn_mfma_f32_16x16x32_bf16(a0, bf, acc[0][t], 0, 0, 0);
            acc[1][t] = __builtin_amdgcn_mfma_f32_16x16x32_bf16(a1, bf, acc[1][t], 0, 0, 0);
        }
    }

    // epilogue: D row = quad*4 + reg, col = t*16 + cl
#pragma unroll
    for (int t = 0; t < 16; ++t) {
        int n = t * 16 + cl;
        float bv = bias[n];
#pragma unroll
        for (int f = 0; f < 2; ++f) {
            int row = mf + f * 16 + quad * 4;
#pragma unroll
            for (int r = 0; r < 4; ++r) {
                if (row + r < NB)
                    out[(long)(row + r) * FO + n] = acc[f][t][r] + bv;
            }
        }
    }
}

extern "C" void kernel_launch(void* const* d_in, const int* in_sizes, int n_in,
                              void* d_out, int out_size, void* d_ws, size_t ws_size,
                              hipStream_t stream) {
    const float* x_self = (const float*)d_in[0];
    const float* feats  = (const float*)d_in[1];
    const int*   idx    = (const int*)d_in[2];
    const float* W      = (const float*)d_in[3];
    const float* bias   = (const float*)d_in[4];
    float* out = (float*)d_out;

    // workspace layout
    unsigned char*  Q   = (unsigned char*)d_ws;                                  // 51.2 MB fp8
    __hip_bfloat16* Hn  = (__hip_bfloat16*)((char*)d_ws + (size_t)NN * FD);      // 25.6 MB bf16
    __hip_bfloat16* Wsw = (__hip_bfloat16*)((char*)d_ws + (size_t)NN * FD
                                                        + (size_t)NB * FD * 2);  // 256 KB

    k_quant_feats<<<NN * FD / 8 / 256, 256, 0, stream>>>(feats, Q);
    k_swizzle_W<<<64, 256, 0, stream>>>(W, Wsw);
    k_gather_mean<<<NB / 4, 256, 0, stream>>>(Q, idx, Hn);
    k_gemm<<<(NB + 63) / 64, 128, 0, stream>>>(x_self, Hn, Wsw, bias, out);
}